// Round 9
// baseline (172.285 us; speedup 1.0000x reference)
//
#include <hip/hip_runtime.h>
#include <hip/hip_bf16.h>

#define NB 32
#define NN 2048
#define DD 64
#define SQC 0.4246613965f  // sqrt(0.125 * LOG2E); applied to both Q and K

typedef __attribute__((ext_vector_type(8))) short short8;
typedef __attribute__((ext_vector_type(16))) float f32x16;
typedef __attribute__((ext_vector_type(4))) unsigned uint4v;
typedef __attribute__((ext_vector_type(4))) int int4v;

#define MFMA32B(A, B, C) \
  __builtin_amdgcn_mfma_f32_32x32x16_bf16((A), (B), (C), 0, 0, 0)

#define GLOAD_LDS16(gp, lp)                                                   \
  __builtin_amdgcn_global_load_lds(                                          \
      (const __attribute__((address_space(1))) void*)(gp),                   \
      (__attribute__((address_space(3))) void*)(lp), 16, 0, 0)

__device__ __forceinline__ short f2bf(float x) {
  __bf16 h = (__bf16)x;
  return __builtin_bit_cast(short, h);
}

__device__ __forceinline__ float fast_exp2(float x) {
#if __has_builtin(__builtin_amdgcn_exp2f)
  return __builtin_amdgcn_exp2f(x);
#else
  return exp2f(x);
#endif
}

// ---- 32x32x16 layouts (A: m=l&31, k=(l>>5)*8+j; B: n=l&31, k=(l>>5)*8+j;
// C: col=l&31, row=(reg&3)+8*(reg>>2)+4*(l>>5)).
// Key permutation: A-row m of a K-fragment holds actual key KEY_OF_ROW(m):
#define KEY_OF_ROW(m) \
  ((((m) >> 3) & 1) * 16 + (((m) >> 2) & 1) * 8 + ((m) >> 4) * 4 + ((m) & 3))
// QK output reg r (lane-half h) maps to key koff(r,h) =
// 16*((r>>2)&1) + 8h + 4*(r>>3) + (r&3); pc0 = regs {0..3,8..11} = keys
// 8h+0..7, pc1 = regs {4..7,12..15} = keys 16+8h+0..7. V natural key order.

// ---------- fused prep (unchanged from flash16): fragment-major bf16 image
// + batch-independent expanded byte-masks, PAIR-INTERLEAVED (masks of chunks
// 2i and 2i+1 adjacent).
__global__ __launch_bounds__(256) void prep_fused(
    const float* __restrict__ x, const int* __restrict__ adj,
    short* __restrict__ img, uint4v* __restrict__ mexp) {
  const int tid = threadIdx.x;
  const int c = blockIdx.x;   // 64-key window -> chunks 2c, 2c+1
  const int b = blockIdx.y;

  // K units (scaled by SQC, permuted rows)
#pragma unroll
  for (int i = 0; i < 2; ++i) {
    const int kc = tid + i * 256;
    const int u8 = kc >> 6, l = kc & 63;
    const int chl = u8 >> 2, dc = u8 & 3;
    const int m = l & 31, hA = l >> 5;
    const int grow = c * 64 + chl * 32 + KEY_OF_ROW(m);
    const float* src = x + ((size_t)(b * NN + grow)) * DD + dc * 16 + 8 * hA;
    float4 f0 = ((const float4*)src)[0];
    float4 f1 = ((const float4*)src)[1];
    short8 v;
    v[0] = f2bf(f0.x * SQC); v[1] = f2bf(f0.y * SQC);
    v[2] = f2bf(f0.z * SQC); v[3] = f2bf(f0.w * SQC);
    v[4] = f2bf(f1.x * SQC); v[5] = f2bf(f1.y * SQC);
    v[6] = f2bf(f1.z * SQC); v[7] = f2bf(f1.w * SQC);
    *(short8*)&img[((size_t)(b * 64 + 2 * c + chl) * 8 + dc) * 512 + l * 8] = v;
  }
  // V units (transposed gather, natural key order)
#pragma unroll
  for (int i = 0; i < 2; ++i) {
    const int vc = tid + i * 256;
    const int u8 = vc >> 6, l = vc & 63;
    const int chl = u8 >> 2, sub = u8 & 3;
    const int dh = sub >> 1, kh = sub & 1;
    const int d = dh * 32 + (l & 31);
    const int key0 = c * 64 + chl * 32 + kh * 16 + 8 * (l >> 5);
    short8 o;
#pragma unroll
    for (int j = 0; j < 8; ++j)
      o[j] = f2bf(x[((size_t)(b * NN + key0 + j)) * DD + d]);
    *(short8*)&img[((size_t)(b * 64 + 2 * c + chl) * 8 + 4 + sub) * 512 +
                   l * 8] = o;
  }

  // expanded masks: block (c,b) -> tile (qg = b>>1, cm = 2c + (b&1))
  if (tid < 128) {
    const int qg = b >> 1;
    const int cm = blockIdx.x * 2 + (b & 1);
    const int ql = tid;
    const int* ap = adj + (size_t)(qg * 128 + ql) * NN + cm * 32;
    int4v av[8];
#pragma unroll
    for (int j = 0; j < 8; ++j) av[j] = *(const int4v*)(ap + j * 4);
#pragma unroll
    for (int h = 0; h < 2; ++h) {
      uint4v mv;
#pragma unroll
      for (int wd = 0; wd < 4; ++wd) {
        unsigned word = 0;
#pragma unroll
        for (int t = 0; t < 4; ++t) {
          const int K = 16 * (wd & 1) + 8 * h + 4 * (wd >> 1) + t;
          word |= (av[K >> 2][K & 3] > 0 ? 0xFFu : 0u) << (8 * t);
        }
        mv[wd] = word;
      }
      mexp[(((size_t)qg * 64 + (cm >> 1) * 2 + h) * 128 + ql) * 2 +
           (cm & 1)] = mv;
    }
  }
}

// masked bf16 pack of one chunk's 16 exp values -> pc0/pc1 B-frags
#define PACK_MASK(EV, MC, PC0, PC1)                                          \
  {                                                                          \
    short8 t0, t1;                                                           \
    t0[0] = f2bf(EV[0]);  t0[1] = f2bf(EV[1]);                               \
    t0[2] = f2bf(EV[2]);  t0[3] = f2bf(EV[3]);                               \
    t0[4] = f2bf(EV[8]);  t0[5] = f2bf(EV[9]);                               \
    t0[6] = f2bf(EV[10]); t0[7] = f2bf(EV[11]);                              \
    t1[0] = f2bf(EV[4]);  t1[1] = f2bf(EV[5]);                               \
    t1[2] = f2bf(EV[6]);  t1[3] = f2bf(EV[7]);                               \
    t1[4] = f2bf(EV[12]); t1[5] = f2bf(EV[13]);                              \
    t1[6] = f2bf(EV[14]); t1[7] = f2bf(EV[15]);                              \
    uint4v u0 = __builtin_bit_cast(uint4v, t0);                              \
    uint4v u1 = __builtin_bit_cast(uint4v, t1);                              \
    u0[0] &= __builtin_amdgcn_perm(0u, MC[0], 0x01010000u);                  \
    u0[1] &= __builtin_amdgcn_perm(0u, MC[0], 0x03030202u);                  \
    u0[2] &= __builtin_amdgcn_perm(0u, MC[2], 0x01010000u);                  \
    u0[3] &= __builtin_amdgcn_perm(0u, MC[2], 0x03030202u);                  \
    u1[0] &= __builtin_amdgcn_perm(0u, MC[1], 0x01010000u);                  \
    u1[1] &= __builtin_amdgcn_perm(0u, MC[1], 0x03030202u);                  \
    u1[2] &= __builtin_amdgcn_perm(0u, MC[3], 0x01010000u);                  \
    u1[3] &= __builtin_amdgcn_perm(0u, MC[3], 0x03030202u);                  \
    PC0 = __builtin_bit_cast(short8, u0);                                    \
    PC1 = __builtin_bit_cast(short8, u1);                                    \
  }

// One superphase m: block computes pair m (wave parity p does chunk 2m+p),
// stages pair m+2 (2 gload_lds/wave), loads own-parity mask of pair m+1.
// VMEM order per wave per phase: 2 gload_lds then 1 mask dwordx4 = 3 ops;
// vmcnt(3) at phase start leaves the previous phase's 3 in flight and
// drains the 2-phase-old staging.  vmcnt BEFORE barrier makes each wave's
// own-staged units globally valid after the barrier (flash14/16 mechanism).
#define PHASE_BODY(SLOT, MUSE, MLOAD, VM, DO_MASK, PAIRM, DO_STAGE, PAIRS,   \
                   SLOTS)                                                    \
  {                                                                          \
    asm volatile("s_waitcnt vmcnt(" VM ")" ::: "memory");                    \
    __builtin_amdgcn_s_barrier();                                            \
    const uint4v mc = MUSE;                                                  \
    if (DO_STAGE) {                                                          \
      const short* gs = img_b + (size_t)(PAIRS) * 8192 + l * 8;              \
      short* ds = &sI[SLOTS][0];                                             \
      GLOAD_LDS16(gs + w * 512, ds + w * 512);                               \
      GLOAD_LDS16(gs + (w + 8) * 512, ds + (w + 8) * 512);                   \
    }                                                                        \
    asm volatile("" ::: "memory");                                           \
    if (DO_MASK)                                                             \
      MLOAD = *(const uint4v*)(mpt + (size_t)(PAIRM) * 8192 + p * 16);       \
    asm volatile("" ::: "memory");                                           \
    __builtin_amdgcn_s_setprio(1);                                           \
    const short* ring = &sI[SLOT][p * 4096];                                 \
    f32x16 s = MFMA32B(*(const short8*)&ring[0 * 512 + l * 8], qf[0], fz);   \
    s = MFMA32B(*(const short8*)&ring[1 * 512 + l * 8], qf[1], s);           \
    s = MFMA32B(*(const short8*)&ring[2 * 512 + l * 8], qf[2], s);           \
    s = MFMA32B(*(const short8*)&ring[3 * 512 + l * 8], qf[3], s);           \
    float e[16];                                                             \
    _Pragma("unroll") for (int r = 0; r < 16; ++r) e[r] = fast_exp2(s[r]);   \
    short8 pc0, pc1;                                                         \
    PACK_MASK(e, mc, pc0, pc1);                                              \
    acl = MFMA32B(ones8, pc0, acl);                                          \
    acl = MFMA32B(ones8, pc1, acl);                                          \
    acc[0] = MFMA32B(*(const short8*)&ring[4 * 512 + l * 8], pc0, acc[0]);   \
    acc[0] = MFMA32B(*(const short8*)&ring[5 * 512 + l * 8], pc1, acc[0]);   \
    acc[1] = MFMA32B(*(const short8*)&ring[6 * 512 + l * 8], pc0, acc[1]);   \
    acc[1] = MFMA32B(*(const short8*)&ring[7 * 512 + l * 8], pc1, acc[1]);   \
    __builtin_amdgcn_s_setprio(0);                                           \
  }

// ---------- main: 512-thread blocks (4 q-tiles x 2 chunk-parities = 8
// waves, 128 q), grid 512 -> 2 blocks/CU = 16 waves/CU (4/SIMD) at the SAME
// per-CU traffic as flash16 (KV staged once per block, shared by parities).
// Ring-3 of 16-KB pairs (48 KB LDS); counted vmcnt(3); parity partials
// merged via LDS at the epilogue. beta&7 = XCD, 4 batches/XCD.
__global__ __launch_bounds__(512, 4) void gat_flash17(
    const float* __restrict__ x, const short* __restrict__ img,
    const char* __restrict__ mexp, float* __restrict__ out) {
  __shared__ short sI[3][8192];

  const int beta = blockIdx.x;
  const int xcd = beta & 7;
  const int idx = beta >> 3;       // 0..63
  const int qg = idx & 15;         // 128-row q-group
  const int b = xcd * 4 + (idx >> 4);

  const int tid = threadIdx.x;
  const int w = tid >> 6;          // 0..7
  const int l = tid & 63;
  const int t = w >> 1;            // q-tile 0..3
  const int p = w & 1;             // chunk parity
  const int h = l >> 5;
  const int ql = t * 32 + (l & 31);
  const int q = qg * 128 + ql;

  const short* img_b = img + (size_t)b * 64 * 8 * 512;
  const char* mpt =
      mexp + ((size_t)((qg * 64 + h) * 128) + ql) * 32;  // pair stride 8192 B

  // Q B-frags from x (scaled by SQC): qf[dc], elem j = Q[q, dc*16+8h+j]*SQC
  short8 qf[4];
  {
    const float* qs = x + ((size_t)(b * NN + q)) * DD + 8 * h;
#pragma unroll
    for (int dc = 0; dc < 4; ++dc) {
      float4 f0 = ((const float4*)(qs + dc * 16))[0];
      float4 f1 = ((const float4*)(qs + dc * 16))[1];
      short8 v;
      v[0] = f2bf(f0.x * SQC); v[1] = f2bf(f0.y * SQC);
      v[2] = f2bf(f0.z * SQC); v[3] = f2bf(f0.w * SQC);
      v[4] = f2bf(f1.x * SQC); v[5] = f2bf(f1.y * SQC);
      v[6] = f2bf(f1.z * SQC); v[7] = f2bf(f1.w * SQC);
      qf[dc] = v;
    }
  }

  f32x16 acc[2], acl, fz;
#pragma unroll
  for (int z = 0; z < 16; ++z) {
    acc[0][z] = 0.f; acc[1][z] = 0.f; acl[z] = 0.f; fz[z] = 0.f;
  }

  short8 ones8;
#pragma unroll
  for (int j = 0; j < 8; ++j) ones8[j] = 0x3F80;

  uint4v mA, mB;

  // prologue: stage pairs 0,1 -> slots 0,1 (2 units/wave each), mask pair 0
  {
    const short* g0 = img_b + l * 8;
    GLOAD_LDS16(g0 + w * 512, &sI[0][w * 512]);
    GLOAD_LDS16(g0 + (w + 8) * 512, &sI[0][(w + 8) * 512]);
    const short* g1 = img_b + 8192 + l * 8;
    GLOAD_LDS16(g1 + w * 512, &sI[1][w * 512]);
    GLOAD_LDS16(g1 + (w + 8) * 512, &sI[1][(w + 8) * 512]);
    asm volatile("" ::: "memory");
    mA = *(const uint4v*)(mpt + (size_t)p * 16);
    asm volatile("" ::: "memory");
  }

  // superphases m=0..31; period-6 pattern (ring-3 x mask-parity-2)
  for (int M = 0; M < 5; ++M) {
    const int m0 = 6 * M;
    PHASE_BODY(0, mA, mB, "3", true, m0 + 1, true, m0 + 2, 2);
    PHASE_BODY(1, mB, mA, "3", true, m0 + 2, true, m0 + 3, 0);
    PHASE_BODY(2, mA, mB, "3", true, m0 + 3, true, m0 + 4, 1);
    PHASE_BODY(0, mB, mA, "3", true, m0 + 4, true, m0 + 5, 2);
    PHASE_BODY(1, mA, mB, "3", true, m0 + 5, true, m0 + 6, 0);
    PHASE_BODY(2, mB, mA, "3", true, m0 + 6, true, m0 + 7, 1);
  }
  PHASE_BODY(0, mA, mB, "3", true, 31, false, 0, 2);   // m=30
  PHASE_BODY(1, mB, mA, "1", false, 0, false, 0, 0);   // m=31

  // ---- epilogue: merge parity partials via LDS, then write ----
  __syncthreads();
  float* red = (float*)sI;
  if (p == 1) {
    float* dst = red + (size_t)(t * 64 + l) * 33;
#pragma unroll
    for (int dh = 0; dh < 2; ++dh)
#pragma unroll
      for (int r = 0; r < 16; ++r) dst[dh * 16 + r] = acc[dh][r];
    dst[32] = acl[0];
  }
  __syncthreads();
  if (p == 0) {
    const float* src = red + (size_t)(t * 64 + l) * 33;
    const float inv = 1.0f / (acl[0] + src[32]);
    float* op = out + ((size_t)(b * NN + q)) * DD;
#pragma unroll
    for (int dh = 0; dh < 2; ++dh)
#pragma unroll
      for (int qd = 0; qd < 4; ++qd) {
        float4 o;
        o.x = (acc[dh][qd * 4 + 0] + src[dh * 16 + qd * 4 + 0]) * inv;
        o.y = (acc[dh][qd * 4 + 1] + src[dh * 16 + qd * 4 + 1]) * inv;
        o.z = (acc[dh][qd * 4 + 2] + src[dh * 16 + qd * 4 + 2]) * inv;
        o.w = (acc[dh][qd * 4 + 3] + src[dh * 16 + qd * 4 + 3]) * inv;
        *(float4*)(op + dh * 32 + 8 * qd + 4 * h) = o;
      }
  }
}

extern "C" void kernel_launch(void* const* d_in, const int* in_sizes, int n_in,
                              void* d_out, int out_size, void* d_ws,
                              size_t ws_size, hipStream_t stream) {
  const float* x = (const float*)d_in[0];
  const int* adj = (const int*)d_in[1];
  float* out = (float*)d_out;

  short* img = (short*)d_ws;                                   // 16 MB
  uint4v* mexp = (uint4v*)(img + (size_t)NB * 64 * 8 * 512);   // 4 MB

  prep_fused<<<dim3(32, NB), 256, 0, stream>>>(x, adj, img, mexp);
  gat_flash17<<<512, 512, 0, stream>>>(x, img, (const char*)mexp, out);
}

// Round 10
// 131.317 us; speedup vs baseline: 1.3120x; 1.3120x over previous
//
#include <hip/hip_runtime.h>
#include <hip/hip_bf16.h>

#define NB 32
#define NN 2048
#define DD 64
#define SQC 0.4246613965f  // sqrt(0.125 * LOG2E); applied to both Q and K

typedef __attribute__((ext_vector_type(8))) short short8;
typedef __attribute__((ext_vector_type(16))) float f32x16;
typedef __attribute__((ext_vector_type(4))) unsigned uint4v;
typedef __attribute__((ext_vector_type(4))) int int4v;

#define MFMA32B(A, B, C) \
  __builtin_amdgcn_mfma_f32_32x32x16_bf16((A), (B), (C), 0, 0, 0)

#define GLOAD_LDS16(gp, lp)                                                   \
  __builtin_amdgcn_global_load_lds(                                          \
      (const __attribute__((address_space(1))) void*)(gp),                   \
      (__attribute__((address_space(3))) void*)(lp), 16, 0, 0)

__device__ __forceinline__ short f2bf(float x) {
  __bf16 h = (__bf16)x;
  return __builtin_bit_cast(short, h);
}

__device__ __forceinline__ float fast_exp2(float x) {
#if __has_builtin(__builtin_amdgcn_exp2f)
  return __builtin_amdgcn_exp2f(x);
#else
  return exp2f(x);
#endif
}

// ---- 32x32x16 layouts (A: m=l&31, k=(l>>5)*8+j; B: n=l&31, k=(l>>5)*8+j;
// C: col=l&31, row=(reg&3)+8*(reg>>2)+4*(l>>5)).
// Key permutation: A-row m of a K-fragment holds actual key KEY_OF_ROW(m):
#define KEY_OF_ROW(m) \
  ((((m) >> 3) & 1) * 16 + (((m) >> 2) & 1) * 8 + ((m) >> 4) * 4 + ((m) & 3))
// QK output reg r (lane-half h) maps to key koff(r,h) =
// 16*((r>>2)&1) + 8h + 4*(r>>3) + (r&3); pc0 = regs {0..3,8..11} = keys
// 8h+0..7, pc1 = regs {4..7,12..15} = keys 16+8h+0..7. V natural key order.

// ---------- fused prep (unchanged): fragment-major bf16 image +
// batch-independent expanded byte-masks, PAIR-INTERLEAVED.
__global__ __launch_bounds__(256) void prep_fused(
    const float* __restrict__ x, const int* __restrict__ adj,
    short* __restrict__ img, uint4v* __restrict__ mexp) {
  const int tid = threadIdx.x;
  const int c = blockIdx.x;   // 64-key window -> chunks 2c, 2c+1
  const int b = blockIdx.y;

  // K units (scaled by SQC, permuted rows)
#pragma unroll
  for (int i = 0; i < 2; ++i) {
    const int kc = tid + i * 256;
    const int u8 = kc >> 6, l = kc & 63;
    const int chl = u8 >> 2, dc = u8 & 3;
    const int m = l & 31, hA = l >> 5;
    const int grow = c * 64 + chl * 32 + KEY_OF_ROW(m);
    const float* src = x + ((size_t)(b * NN + grow)) * DD + dc * 16 + 8 * hA;
    float4 f0 = ((const float4*)src)[0];
    float4 f1 = ((const float4*)src)[1];
    short8 v;
    v[0] = f2bf(f0.x * SQC); v[1] = f2bf(f0.y * SQC);
    v[2] = f2bf(f0.z * SQC); v[3] = f2bf(f0.w * SQC);
    v[4] = f2bf(f1.x * SQC); v[5] = f2bf(f1.y * SQC);
    v[6] = f2bf(f1.z * SQC); v[7] = f2bf(f1.w * SQC);
    *(short8*)&img[((size_t)(b * 64 + 2 * c + chl) * 8 + dc) * 512 + l * 8] = v;
  }
  // V units (transposed gather, natural key order)
#pragma unroll
  for (int i = 0; i < 2; ++i) {
    const int vc = tid + i * 256;
    const int u8 = vc >> 6, l = vc & 63;
    const int chl = u8 >> 2, sub = u8 & 3;
    const int dh = sub >> 1, kh = sub & 1;
    const int d = dh * 32 + (l & 31);
    const int key0 = c * 64 + chl * 32 + kh * 16 + 8 * (l >> 5);
    short8 o;
#pragma unroll
    for (int j = 0; j < 8; ++j)
      o[j] = f2bf(x[((size_t)(b * NN + key0 + j)) * DD + d]);
    *(short8*)&img[((size_t)(b * 64 + 2 * c + chl) * 8 + 4 + sub) * 512 +
                   l * 8] = o;
  }

  // expanded masks: block (c,b) -> tile (qg = b>>1, cm = 2c + (b&1))
  if (tid < 128) {
    const int qg = b >> 1;
    const int cm = blockIdx.x * 2 + (b & 1);
    const int ql = tid;
    const int* ap = adj + (size_t)(qg * 128 + ql) * NN + cm * 32;
    int4v av[8];
#pragma unroll
    for (int j = 0; j < 8; ++j) av[j] = *(const int4v*)(ap + j * 4);
#pragma unroll
    for (int h = 0; h < 2; ++h) {
      uint4v mv;
#pragma unroll
      for (int wd = 0; wd < 4; ++wd) {
        unsigned word = 0;
#pragma unroll
        for (int t = 0; t < 4; ++t) {
          const int K = 16 * (wd & 1) + 8 * h + 4 * (wd >> 1) + t;
          word |= (av[K >> 2][K & 3] > 0 ? 0xFFu : 0u) << (8 * t);
        }
        mv[wd] = word;
      }
      mexp[(((size_t)qg * 64 + (cm >> 1) * 2 + h) * 128 + ql) * 2 +
           (cm & 1)] = mv;
    }
  }
}

// masked bf16 pack of one chunk's 16 exp values -> pc0/pc1 B-frags
#define PACK_MASK(EV, MC, PC0, PC1)                                          \
  {                                                                          \
    short8 t0, t1;                                                           \
    t0[0] = f2bf(EV[0]);  t0[1] = f2bf(EV[1]);                               \
    t0[2] = f2bf(EV[2]);  t0[3] = f2bf(EV[3]);                               \
    t0[4] = f2bf(EV[8]);  t0[5] = f2bf(EV[9]);                               \
    t0[6] = f2bf(EV[10]); t0[7] = f2bf(EV[11]);                              \
    t1[0] = f2bf(EV[4]);  t1[1] = f2bf(EV[5]);                               \
    t1[2] = f2bf(EV[6]);  t1[3] = f2bf(EV[7]);                               \
    t1[4] = f2bf(EV[12]); t1[5] = f2bf(EV[13]);                              \
    t1[6] = f2bf(EV[14]); t1[7] = f2bf(EV[15]);                              \
    uint4v u0 = __builtin_bit_cast(uint4v, t0);                              \
    uint4v u1 = __builtin_bit_cast(uint4v, t1);                              \
    u0[0] &= __builtin_amdgcn_perm(0u, MC[0], 0x01010000u);                  \
    u0[1] &= __builtin_amdgcn_perm(0u, MC[0], 0x03030202u);                  \
    u0[2] &= __builtin_amdgcn_perm(0u, MC[2], 0x01010000u);                  \
    u0[3] &= __builtin_amdgcn_perm(0u, MC[2], 0x03030202u);                  \
    u1[0] &= __builtin_amdgcn_perm(0u, MC[1], 0x01010000u);                  \
    u1[1] &= __builtin_amdgcn_perm(0u, MC[1], 0x03030202u);                  \
    u1[2] &= __builtin_amdgcn_perm(0u, MC[3], 0x01010000u);                  \
    u1[3] &= __builtin_amdgcn_perm(0u, MC[3], 0x03030202u);                  \
    PC0 = __builtin_bit_cast(short8, u0);                                    \
    PC1 = __builtin_bit_cast(short8, u1);                                    \
  }

// One superphase m: block computes pair m (wave parity p does chunk 2m+p),
// stages pair m+2 (2 gload_lds/wave), loads own-parity mask of pair m+1.
// VMEM order per wave per phase: 2 gload_lds then 1 mask dwordx4 = 3 ops;
// vmcnt(3) at phase start leaves the previous phase's 3 in flight and
// drains the 2-phase-old staging.  vmcnt BEFORE barrier makes each wave's
// own-staged units globally valid after the barrier.
#define PHASE_BODY(SLOT, MUSE, MLOAD, VM, DO_MASK, PAIRM, DO_STAGE, PAIRS,   \
                   SLOTS)                                                    \
  {                                                                          \
    asm volatile("s_waitcnt vmcnt(" VM ")" ::: "memory");                    \
    __builtin_amdgcn_s_barrier();                                            \
    const uint4v mc = MUSE;                                                  \
    if (DO_STAGE) {                                                          \
      const short* gs = img_b + (size_t)(PAIRS) * 8192 + l * 8;              \
      short* ds = &sI[SLOTS][0];                                             \
      GLOAD_LDS16(gs + w * 512, ds + w * 512);                               \
      GLOAD_LDS16(gs + (w + 8) * 512, ds + (w + 8) * 512);                   \
    }                                                                        \
    asm volatile("" ::: "memory");                                           \
    if (DO_MASK)                                                             \
      MLOAD = *(const uint4v*)(mpt + (size_t)(PAIRM) * 8192 + p * 16);       \
    asm volatile("" ::: "memory");                                           \
    __builtin_amdgcn_s_setprio(1);                                           \
    const short* ring = &sI[SLOT][p * 4096];                                 \
    f32x16 s = MFMA32B(*(const short8*)&ring[0 * 512 + l * 8], qf[0], fz);   \
    s = MFMA32B(*(const short8*)&ring[1 * 512 + l * 8], qf[1], s);           \
    s = MFMA32B(*(const short8*)&ring[2 * 512 + l * 8], qf[2], s);           \
    s = MFMA32B(*(const short8*)&ring[3 * 512 + l * 8], qf[3], s);           \
    float e[16];                                                             \
    _Pragma("unroll") for (int r = 0; r < 16; ++r) e[r] = fast_exp2(s[r]);   \
    short8 pc0, pc1;                                                         \
    PACK_MASK(e, mc, pc0, pc1);                                              \
    acl = MFMA32B(ones8, pc0, acl);                                          \
    acl = MFMA32B(ones8, pc1, acl);                                          \
    acc[0] = MFMA32B(*(const short8*)&ring[4 * 512 + l * 8], pc0, acc[0]);   \
    acc[0] = MFMA32B(*(const short8*)&ring[5 * 512 + l * 8], pc1, acc[0]);   \
    acc[1] = MFMA32B(*(const short8*)&ring[6 * 512 + l * 8], pc0, acc[1]);   \
    acc[1] = MFMA32B(*(const short8*)&ring[7 * 512 + l * 8], pc1, acc[1]);   \
    __builtin_amdgcn_s_setprio(0);                                           \
  }

// ---------- main: identical to flash17 EXCEPT __launch_bounds__(512, 2) —
// round 9's (512,4) capped the allocator at 64 VGPR and spilled ~300 MB to
// scratch (FETCH 150 MB / WRITE 191 MB). With the cap at ~128-256 VGPR the
// kernel holds its ~110 live regs in-register; at <=128 VGPR the HW still
// fits 2 blocks/CU = 16 waves/CU — the intended TLP-at-constant-traffic
// experiment. beta&7 = XCD, 4 batches/XCD.
__global__ __launch_bounds__(512, 2) void gat_flash18(
    const float* __restrict__ x, const short* __restrict__ img,
    const char* __restrict__ mexp, float* __restrict__ out) {
  __shared__ short sI[3][8192];

  const int beta = blockIdx.x;
  const int xcd = beta & 7;
  const int idx = beta >> 3;       // 0..63
  const int qg = idx & 15;         // 128-row q-group
  const int b = xcd * 4 + (idx >> 4);

  const int tid = threadIdx.x;
  const int w = tid >> 6;          // 0..7
  const int l = tid & 63;
  const int t = w >> 1;            // q-tile 0..3
  const int p = w & 1;             // chunk parity
  const int h = l >> 5;
  const int ql = t * 32 + (l & 31);
  const int q = qg * 128 + ql;

  const short* img_b = img + (size_t)b * 64 * 8 * 512;
  const char* mpt =
      mexp + ((size_t)((qg * 64 + h) * 128) + ql) * 32;  // pair stride 8192 B

  // Q B-frags from x (scaled by SQC): qf[dc], elem j = Q[q, dc*16+8h+j]*SQC
  short8 qf[4];
  {
    const float* qs = x + ((size_t)(b * NN + q)) * DD + 8 * h;
#pragma unroll
    for (int dc = 0; dc < 4; ++dc) {
      float4 f0 = ((const float4*)(qs + dc * 16))[0];
      float4 f1 = ((const float4*)(qs + dc * 16))[1];
      short8 v;
      v[0] = f2bf(f0.x * SQC); v[1] = f2bf(f0.y * SQC);
      v[2] = f2bf(f0.z * SQC); v[3] = f2bf(f0.w * SQC);
      v[4] = f2bf(f1.x * SQC); v[5] = f2bf(f1.y * SQC);
      v[6] = f2bf(f1.z * SQC); v[7] = f2bf(f1.w * SQC);
      qf[dc] = v;
    }
  }

  f32x16 acc[2], acl, fz;
#pragma unroll
  for (int z = 0; z < 16; ++z) {
    acc[0][z] = 0.f; acc[1][z] = 0.f; acl[z] = 0.f; fz[z] = 0.f;
  }

  short8 ones8;
#pragma unroll
  for (int j = 0; j < 8; ++j) ones8[j] = 0x3F80;

  uint4v mA, mB;

  // prologue: stage pairs 0,1 -> slots 0,1 (2 units/wave each), mask pair 0
  {
    const short* g0 = img_b + l * 8;
    GLOAD_LDS16(g0 + w * 512, &sI[0][w * 512]);
    GLOAD_LDS16(g0 + (w + 8) * 512, &sI[0][(w + 8) * 512]);
    const short* g1 = img_b + 8192 + l * 8;
    GLOAD_LDS16(g1 + w * 512, &sI[1][w * 512]);
    GLOAD_LDS16(g1 + (w + 8) * 512, &sI[1][(w + 8) * 512]);
    asm volatile("" ::: "memory");
    mA = *(const uint4v*)(mpt + (size_t)p * 16);
    asm volatile("" ::: "memory");
  }

  // superphases m=0..31; period-6 pattern (ring-3 x mask-parity-2)
  for (int M = 0; M < 5; ++M) {
    const int m0 = 6 * M;
    PHASE_BODY(0, mA, mB, "3", true, m0 + 1, true, m0 + 2, 2);
    PHASE_BODY(1, mB, mA, "3", true, m0 + 2, true, m0 + 3, 0);
    PHASE_BODY(2, mA, mB, "3", true, m0 + 3, true, m0 + 4, 1);
    PHASE_BODY(0, mB, mA, "3", true, m0 + 4, true, m0 + 5, 2);
    PHASE_BODY(1, mA, mB, "3", true, m0 + 5, true, m0 + 6, 0);
    PHASE_BODY(2, mB, mA, "3", true, m0 + 6, true, m0 + 7, 1);
  }
  PHASE_BODY(0, mA, mB, "3", true, 31, false, 0, 2);   // m=30
  PHASE_BODY(1, mB, mA, "1", false, 0, false, 0, 0);   // m=31

  // ---- epilogue: merge parity partials via LDS, then write ----
  __syncthreads();
  float* red = (float*)sI;
  if (p == 1) {
    float* dst = red + (size_t)(t * 64 + l) * 33;
#pragma unroll
    for (int dh = 0; dh < 2; ++dh)
#pragma unroll
      for (int r = 0; r < 16; ++r) dst[dh * 16 + r] = acc[dh][r];
    dst[32] = acl[0];
  }
  __syncthreads();
  if (p == 0) {
    const float* src = red + (size_t)(t * 64 + l) * 33;
    const float inv = 1.0f / (acl[0] + src[32]);
    float* op = out + ((size_t)(b * NN + q)) * DD;
#pragma unroll
    for (int dh = 0; dh < 2; ++dh)
#pragma unroll
      for (int qd = 0; qd < 4; ++qd) {
        float4 o;
        o.x = (acc[dh][qd * 4 + 0] + src[dh * 16 + qd * 4 + 0]) * inv;
        o.y = (acc[dh][qd * 4 + 1] + src[dh * 16 + qd * 4 + 1]) * inv;
        o.z = (acc[dh][qd * 4 + 2] + src[dh * 16 + qd * 4 + 2]) * inv;
        o.w = (acc[dh][qd * 4 + 3] + src[dh * 16 + qd * 4 + 3]) * inv;
        *(float4*)(op + dh * 32 + 8 * qd + 4 * h) = o;
      }
  }
}

extern "C" void kernel_launch(void* const* d_in, const int* in_sizes, int n_in,
                              void* d_out, int out_size, void* d_ws,
                              size_t ws_size, hipStream_t stream) {
  const float* x = (const float*)d_in[0];
  const int* adj = (const int*)d_in[1];
  float* out = (float*)d_out;

  short* img = (short*)d_ws;                                   // 16 MB
  uint4v* mexp = (uint4v*)(img + (size_t)NB * 64 * 8 * 512);   // 4 MB

  prep_fused<<<dim3(32, NB), 256, 0, stream>>>(x, adj, img, mexp);
  gat_flash18<<<512, 512, 0, stream>>>(x, img, (const char*)mexp, out);
}

// Round 11
// 125.380 us; speedup vs baseline: 1.3741x; 1.0473x over previous
//
#include <hip/hip_runtime.h>
#include <hip/hip_bf16.h>

#define NB 32
#define NN 2048
#define DD 64
#define SQC 0.4246613965f  // sqrt(0.125 * LOG2E); applied to both Q and K

typedef __attribute__((ext_vector_type(8))) short short8;
typedef __attribute__((ext_vector_type(16))) float f32x16;
typedef __attribute__((ext_vector_type(4))) unsigned uint4v;
typedef __attribute__((ext_vector_type(4))) int int4v;

#define MFMA32B(A, B, C) \
  __builtin_amdgcn_mfma_f32_32x32x16_bf16((A), (B), (C), 0, 0, 0)

#define GLOAD_LDS16(gp, lp)                                                   \
  __builtin_amdgcn_global_load_lds(                                          \
      (const __attribute__((address_space(1))) void*)(gp),                   \
      (__attribute__((address_space(3))) void*)(lp), 16, 0, 0)

__device__ __forceinline__ short f2bf(float x) {
  __bf16 h = (__bf16)x;
  return __builtin_bit_cast(short, h);
}

__device__ __forceinline__ float fast_exp2(float x) {
#if __has_builtin(__builtin_amdgcn_exp2f)
  return __builtin_amdgcn_exp2f(x);
#else
  return exp2f(x);
#endif
}

// ---- 32x32x16 layouts (A: m=l&31, k=(l>>5)*8+j; B: n=l&31, k=(l>>5)*8+j;
// C: col=l&31, row=(reg&3)+8*(reg>>2)+4*(l>>5)).
// Key permutation: A-row m of a K-fragment holds actual key KEY_OF_ROW(m):
#define KEY_OF_ROW(m) \
  ((((m) >> 3) & 1) * 16 + (((m) >> 2) & 1) * 8 + ((m) >> 4) * 4 + ((m) & 3))
// QK output reg r (lane-half h) maps to key koff(r,h) =
// 16*((r>>2)&1) + 8h + 4*(r>>3) + (r&3); pc0 = regs {0..3,8..11} = keys
// 8h+0..7, pc1 = regs {4..7,12..15} = keys 16+8h+0..7. V natural key order.

// ---------- fused prep (unchanged): fragment-major bf16 image +
// batch-independent expanded byte-masks, PAIR-INTERLEAVED.
__global__ __launch_bounds__(256) void prep_fused(
    const float* __restrict__ x, const int* __restrict__ adj,
    short* __restrict__ img, uint4v* __restrict__ mexp) {
  const int tid = threadIdx.x;
  const int c = blockIdx.x;   // 64-key window -> chunks 2c, 2c+1
  const int b = blockIdx.y;

  // K units (scaled by SQC, permuted rows)
#pragma unroll
  for (int i = 0; i < 2; ++i) {
    const int kc = tid + i * 256;
    const int u8 = kc >> 6, l = kc & 63;
    const int chl = u8 >> 2, dc = u8 & 3;
    const int m = l & 31, hA = l >> 5;
    const int grow = c * 64 + chl * 32 + KEY_OF_ROW(m);
    const float* src = x + ((size_t)(b * NN + grow)) * DD + dc * 16 + 8 * hA;
    float4 f0 = ((const float4*)src)[0];
    float4 f1 = ((const float4*)src)[1];
    short8 v;
    v[0] = f2bf(f0.x * SQC); v[1] = f2bf(f0.y * SQC);
    v[2] = f2bf(f0.z * SQC); v[3] = f2bf(f0.w * SQC);
    v[4] = f2bf(f1.x * SQC); v[5] = f2bf(f1.y * SQC);
    v[6] = f2bf(f1.z * SQC); v[7] = f2bf(f1.w * SQC);
    *(short8*)&img[((size_t)(b * 64 + 2 * c + chl) * 8 + dc) * 512 + l * 8] = v;
  }
  // V units (transposed gather, natural key order)
#pragma unroll
  for (int i = 0; i < 2; ++i) {
    const int vc = tid + i * 256;
    const int u8 = vc >> 6, l = vc & 63;
    const int chl = u8 >> 2, sub = u8 & 3;
    const int dh = sub >> 1, kh = sub & 1;
    const int d = dh * 32 + (l & 31);
    const int key0 = c * 64 + chl * 32 + kh * 16 + 8 * (l >> 5);
    short8 o;
#pragma unroll
    for (int j = 0; j < 8; ++j)
      o[j] = f2bf(x[((size_t)(b * NN + key0 + j)) * DD + d]);
    *(short8*)&img[((size_t)(b * 64 + 2 * c + chl) * 8 + 4 + sub) * 512 +
                   l * 8] = o;
  }

  // expanded masks: block (c,b) -> tile (qg = b>>1, cm = 2c + (b&1))
  if (tid < 128) {
    const int qg = b >> 1;
    const int cm = blockIdx.x * 2 + (b & 1);
    const int ql = tid;
    const int* ap = adj + (size_t)(qg * 128 + ql) * NN + cm * 32;
    int4v av[8];
#pragma unroll
    for (int j = 0; j < 8; ++j) av[j] = *(const int4v*)(ap + j * 4);
#pragma unroll
    for (int h = 0; h < 2; ++h) {
      uint4v mv;
#pragma unroll
      for (int wd = 0; wd < 4; ++wd) {
        unsigned word = 0;
#pragma unroll
        for (int t = 0; t < 4; ++t) {
          const int K = 16 * (wd & 1) + 8 * h + 4 * (wd >> 1) + t;
          word |= (av[K >> 2][K & 3] > 0 ? 0xFFu : 0u) << (8 * t);
        }
        mv[wd] = word;
      }
      mexp[(((size_t)qg * 64 + (cm >> 1) * 2 + h) * 128 + ql) * 2 +
           (cm & 1)] = mv;
    }
  }
}

// masked bf16 pack of one chunk's 16 exp values -> pc0/pc1 B-frags
#define PACK_MASK(EV, MC, PC0, PC1)                                          \
  {                                                                          \
    short8 t0, t1;                                                           \
    t0[0] = f2bf(EV[0]);  t0[1] = f2bf(EV[1]);                               \
    t0[2] = f2bf(EV[2]);  t0[3] = f2bf(EV[3]);                               \
    t0[4] = f2bf(EV[8]);  t0[5] = f2bf(EV[9]);                               \
    t0[6] = f2bf(EV[10]); t0[7] = f2bf(EV[11]);                              \
    t1[0] = f2bf(EV[4]);  t1[1] = f2bf(EV[5]);                               \
    t1[2] = f2bf(EV[6]);  t1[3] = f2bf(EV[7]);                               \
    t1[4] = f2bf(EV[12]); t1[5] = f2bf(EV[13]);                              \
    t1[6] = f2bf(EV[14]); t1[7] = f2bf(EV[15]);                              \
    uint4v u0 = __builtin_bit_cast(uint4v, t0);                              \
    uint4v u1 = __builtin_bit_cast(uint4v, t1);                              \
    u0[0] &= __builtin_amdgcn_perm(0u, MC[0], 0x01010000u);                  \
    u0[1] &= __builtin_amdgcn_perm(0u, MC[0], 0x03030202u);                  \
    u0[2] &= __builtin_amdgcn_perm(0u, MC[2], 0x01010000u);                  \
    u0[3] &= __builtin_amdgcn_perm(0u, MC[2], 0x03030202u);                  \
    u1[0] &= __builtin_amdgcn_perm(0u, MC[1], 0x01010000u);                  \
    u1[1] &= __builtin_amdgcn_perm(0u, MC[1], 0x03030202u);                  \
    u1[2] &= __builtin_amdgcn_perm(0u, MC[3], 0x01010000u);                  \
    u1[3] &= __builtin_amdgcn_perm(0u, MC[3], 0x03030202u);                  \
    PC0 = __builtin_bit_cast(short8, u0);                                    \
    PC1 = __builtin_bit_cast(short8, u1);                                    \
  }

// stage one 16-KB pair (16 units of 1 KB) split across 4 waves -> ring slot
#define STAGE_PAIR(PAIR)                                                     \
  {                                                                          \
    const short* gs_ = img_b + (size_t)(PAIR) * 8192 + l * 8;                \
    short* ds_ = &sI[(PAIR) & 3][0];                                         \
    GLOAD_LDS16(gs_ + (w + 0) * 512, ds_ + (w + 0) * 512);                   \
    GLOAD_LDS16(gs_ + (w + 4) * 512, ds_ + (w + 4) * 512);                   \
    GLOAD_LDS16(gs_ + (w + 8) * 512, ds_ + (w + 8) * 512);                   \
    GLOAD_LDS16(gs_ + (w + 12) * 512, ds_ + (w + 12) * 512);                 \
  }

#define MASK_LOAD(ME, MO, PAIR)                                              \
  ME = *(const uint4v*)(mpt + (size_t)(PAIR) * 8192);                        \
  MO = *(const uint4v*)(mpt + (size_t)(PAIR) * 8192 + 16);

// QK of pair (2 chunks E/O) from ring slot KS -> score regs SE/SO (8 MFMA)
#define QK_BLOCK(SE, SO, KS)                                                 \
  {                                                                          \
    const short* rE_ = &sI[KS][0];                                           \
    const short* rO_ = &sI[KS][4096];                                        \
    SE = MFMA32B(*(const short8*)&rE_[0 * 512 + l * 8], qf[0], fz);          \
    SO = MFMA32B(*(const short8*)&rO_[0 * 512 + l * 8], qf[0], fz);          \
    SE = MFMA32B(*(const short8*)&rE_[1 * 512 + l * 8], qf[1], SE);          \
    SO = MFMA32B(*(const short8*)&rO_[1 * 512 + l * 8], qf[1], SO);          \
    SE = MFMA32B(*(const short8*)&rE_[2 * 512 + l * 8], qf[2], SE);          \
    SO = MFMA32B(*(const short8*)&rO_[2 * 512 + l * 8], qf[2], SO);          \
    SE = MFMA32B(*(const short8*)&rE_[3 * 512 + l * 8], qf[3], SE);          \
    SO = MFMA32B(*(const short8*)&rO_[3 * 512 + l * 8], qf[3], SO);          \
  }

// deferred finish of a pair: exp/pack/mask + rowsum + PV from V of slot VS
#define FINISH_BLOCK(SE, SO, ME, MO, VS)                                     \
  {                                                                          \
    float eE_[16], eO_[16];                                                  \
    _Pragma("unroll") for (int r = 0; r < 16; ++r) {                         \
      eE_[r] = fast_exp2(SE[r]);                                             \
      eO_[r] = fast_exp2(SO[r]);                                             \
    }                                                                        \
    short8 p0E_, p1E_, p0O_, p1O_;                                           \
    PACK_MASK(eE_, ME, p0E_, p1E_);                                          \
    PACK_MASK(eO_, MO, p0O_, p1O_);                                          \
    acl = MFMA32B(ones8, p0E_, acl);                                         \
    acl = MFMA32B(ones8, p1E_, acl);                                         \
    acl = MFMA32B(ones8, p0O_, acl);                                         \
    acl = MFMA32B(ones8, p1O_, acl);                                         \
    const short* vE_ = &sI[VS][0];                                           \
    const short* vO_ = &sI[VS][4096];                                        \
    acc[0] = MFMA32B(*(const short8*)&vE_[4 * 512 + l * 8], p0E_, acc[0]);   \
    acc[1] = MFMA32B(*(const short8*)&vE_[6 * 512 + l * 8], p0E_, acc[1]);   \
    acc[0] = MFMA32B(*(const short8*)&vE_[5 * 512 + l * 8], p1E_, acc[0]);   \
    acc[1] = MFMA32B(*(const short8*)&vE_[7 * 512 + l * 8], p1E_, acc[1]);   \
    acc[0] = MFMA32B(*(const short8*)&vO_[4 * 512 + l * 8], p0O_, acc[0]);   \
    acc[1] = MFMA32B(*(const short8*)&vO_[6 * 512 + l * 8], p0O_, acc[1]);   \
    acc[0] = MFMA32B(*(const short8*)&vO_[5 * 512 + l * 8], p1O_, acc[0]);   \
    acc[1] = MFMA32B(*(const short8*)&vO_[7 * 512 + l * 8], p1O_, acc[1]);   \
  }

// ---------- main: flash16 footprint (512 blocks x 4 waves, 2 blocks/CU)
// with CROSS-PHASE softmax pipelining (T15): phase m runs QK(m) on the MFMA
// pipe while finish(m-1) (exp2/pack/mask/rowsum/PV) runs on VALU/TRANS —
// the two stages are register-independent so the pipes overlap instead of
// serializing inside each barrier pair. Ring-4 of 16-KB pairs (64 KB LDS);
// counted vmcnt(6) (1 phase of 4 gload + 2 mask always in flight); static
// sA/sB score-register alternation; masks in 2 rotating sets loaded at
// phase end (after their previous use). beta&7 = XCD, 4 batches/XCD.
__global__ __launch_bounds__(256, 2) void gat_flash19(
    const float* __restrict__ x, const short* __restrict__ img,
    const char* __restrict__ mexp, float* __restrict__ out) {
  __shared__ short sI[4][8192];  // ring-4 of 16-KB pairs

  const int beta = blockIdx.x;
  const int xcd = beta & 7;
  const int idx = beta >> 3;       // 0..63
  const int qg = idx & 15;         // 128-row q-group
  const int b = xcd * 4 + (idx >> 4);

  const int tid = threadIdx.x;
  const int w = tid >> 6;          // 0..3
  const int l = tid & 63;
  const int h = l >> 5;
  const int ql = w * 32 + (l & 31);
  const int q = qg * 128 + ql;

  const short* img_b = img + (size_t)b * 64 * 8 * 512;
  const char* mpt =
      mexp + ((size_t)((qg * 64 + h) * 128) + ql) * 32;  // pair stride 8192 B

  // Q B-frags from x (scaled by SQC): qf[dc], elem j = Q[q, dc*16+8h+j]*SQC
  short8 qf[4];
  {
    const float* qs = x + ((size_t)(b * NN + q)) * DD + 8 * h;
#pragma unroll
    for (int dc = 0; dc < 4; ++dc) {
      float4 f0 = ((const float4*)(qs + dc * 16))[0];
      float4 f1 = ((const float4*)(qs + dc * 16))[1];
      short8 v;
      v[0] = f2bf(f0.x * SQC); v[1] = f2bf(f0.y * SQC);
      v[2] = f2bf(f0.z * SQC); v[3] = f2bf(f0.w * SQC);
      v[4] = f2bf(f1.x * SQC); v[5] = f2bf(f1.y * SQC);
      v[6] = f2bf(f1.z * SQC); v[7] = f2bf(f1.w * SQC);
      qf[dc] = v;
    }
  }

  f32x16 acc[2], acl, fz;
#pragma unroll
  for (int z = 0; z < 16; ++z) {
    acc[0][z] = 0.f; acc[1][z] = 0.f; acl[z] = 0.f; fz[z] = 0.f;
  }

  short8 ones8;
#pragma unroll
  for (int j = 0; j < 8; ++j) ones8[j] = 0x3F80;

  f32x16 sAE, sAO, sBE, sBO;       // two pairs of score regs (static names)
  uint4v mEvE, mEvO, mOdE, mOdO;   // rotating mask sets (even/odd pairs)

  // ---- prologue: masks(0), stage pairs 0,1 ----
  MASK_LOAD(mEvE, mEvO, 0);
  asm volatile("" ::: "memory");
  STAGE_PAIR(0);
  STAGE_PAIR(1);
  asm volatile("" ::: "memory");

  // ---- phase 0: QK(0) only (nothing to finish) ----
  asm volatile("s_waitcnt vmcnt(4)" ::: "memory");  // pair0 + masks0 done
  __builtin_amdgcn_s_barrier();
  STAGE_PAIR(2);
  asm volatile("" ::: "memory");
  __builtin_amdgcn_s_setprio(1);
  QK_BLOCK(sAE, sAO, 0);
  __builtin_amdgcn_s_setprio(0);
  asm volatile("" ::: "memory");
  MASK_LOAD(mOdE, mOdO, 1);

  // ---- phases 1..30: QK(m) || finish(m-1) ----
  for (int j = 0; j < 15; ++j) {
    // phase m = 2j+1: QK -> sB, finish sA (even pair 2j)
    asm volatile("s_waitcnt vmcnt(6)" ::: "memory");
    __builtin_amdgcn_s_barrier();
    STAGE_PAIR(2 * j + 3);
    asm volatile("" ::: "memory");
    __builtin_amdgcn_s_setprio(1);
    QK_BLOCK(sBE, sBO, (2 * j + 1) & 3);
    FINISH_BLOCK(sAE, sAO, mEvE, mEvO, (2 * j) & 3);
    __builtin_amdgcn_s_setprio(0);
    asm volatile("" ::: "memory");
    MASK_LOAD(mEvE, mEvO, 2 * j + 2);

    // phase m = 2j+2: QK -> sA, finish sB (odd pair 2j+1)
    asm volatile("s_waitcnt vmcnt(6)" ::: "memory");
    __builtin_amdgcn_s_barrier();
    if (j < 14) { STAGE_PAIR(2 * j + 4); }
    asm volatile("" ::: "memory");
    __builtin_amdgcn_s_setprio(1);
    QK_BLOCK(sAE, sAO, (2 * j + 2) & 3);
    FINISH_BLOCK(sBE, sBO, mOdE, mOdO, (2 * j + 1) & 3);
    __builtin_amdgcn_s_setprio(0);
    asm volatile("" ::: "memory");
    MASK_LOAD(mOdE, mOdO, 2 * j + 3);
  }

  // ---- phase 31: QK(31) || finish(30) ----
  asm volatile("s_waitcnt vmcnt(2)" ::: "memory");  // pair31 + masks(30) done
  __builtin_amdgcn_s_barrier();
  __builtin_amdgcn_s_setprio(1);
  QK_BLOCK(sBE, sBO, 3);
  FINISH_BLOCK(sAE, sAO, mEvE, mEvO, 2);
  __builtin_amdgcn_s_setprio(0);

  // ---- epilogue: finish(31) (compiler waits on masks(31) regs) ----
  FINISH_BLOCK(sBE, sBO, mOdE, mOdO, 3);

  const float inv = 1.0f / acl[0];
  float* op = out + ((size_t)(b * NN + q)) * DD;
#pragma unroll
  for (int dh = 0; dh < 2; ++dh)
#pragma unroll
    for (int qd = 0; qd < 4; ++qd) {
      float4 o;
      o.x = acc[dh][qd * 4 + 0] * inv;
      o.y = acc[dh][qd * 4 + 1] * inv;
      o.z = acc[dh][qd * 4 + 2] * inv;
      o.w = acc[dh][qd * 4 + 3] * inv;
      *(float4*)(op + dh * 32 + 8 * qd + 4 * h) = o;
    }
}

extern "C" void kernel_launch(void* const* d_in, const int* in_sizes, int n_in,
                              void* d_out, int out_size, void* d_ws,
                              size_t ws_size, hipStream_t stream) {
  const float* x = (const float*)d_in[0];
  const int* adj = (const int*)d_in[1];
  float* out = (float*)d_out;

  short* img = (short*)d_ws;                                   // 16 MB
  uint4v* mexp = (uint4v*)(img + (size_t)NB * 64 * 8 * 512);   // 4 MB

  prep_fused<<<dim3(32, NB), 256, 0, stream>>>(x, adj, img, mexp);
  gat_flash19<<<512, 256, 0, stream>>>(x, img, (const char*)mexp, out);
}

// Round 12
// 125.329 us; speedup vs baseline: 1.3747x; 1.0004x over previous
//
#include <hip/hip_runtime.h>
#include <hip/hip_bf16.h>

#define NB 32
#define NN 2048
#define DD 64
#define SQC 0.4246613965f  // sqrt(0.125 * LOG2E); applied to both Q and K

typedef __attribute__((ext_vector_type(8))) short short8;
typedef __attribute__((ext_vector_type(16))) float f32x16;
typedef __attribute__((ext_vector_type(4))) unsigned uint4v;
typedef __attribute__((ext_vector_type(4))) int int4v;

#define MFMA32B(A, B, C) \
  __builtin_amdgcn_mfma_f32_32x32x16_bf16((A), (B), (C), 0, 0, 0)

#define GLOAD_LDS16(gp, lp)                                                   \
  __builtin_amdgcn_global_load_lds(                                          \
      (const __attribute__((address_space(1))) void*)(gp),                   \
      (__attribute__((address_space(3))) void*)(lp), 16, 0, 0)

__device__ __forceinline__ short f2bf(float x) {
  __bf16 h = (__bf16)x;
  return __builtin_bit_cast(short, h);
}

__device__ __forceinline__ float fast_exp2(float x) {
#if __has_builtin(__builtin_amdgcn_exp2f)
  return __builtin_amdgcn_exp2f(x);
#else
  return exp2f(x);
#endif
}

// ---- 32x32x16 layouts (A: m=l&31, k=(l>>5)*8+j; B: n=l&31, k=(l>>5)*8+j;
// C: col=l&31, row=(reg&3)+8*(reg>>2)+4*(l>>5)).
// Key permutation: A-row m of a K-fragment holds actual key KEY_OF_ROW(m):
#define KEY_OF_ROW(m) \
  ((((m) >> 3) & 1) * 16 + (((m) >> 2) & 1) * 8 + ((m) >> 4) * 4 + ((m) & 3))
// QK output reg r (lane-half h) maps to key koff(r,h) =
// 16*((r>>2)&1) + 8h + 4*(r>>3) + (r&3); pc0 = regs {0..3,8..11} = keys
// 8h+0..7, pc1 = regs {4..7,12..15} = keys 16+8h+0..7. V natural key order.

// ---------- prep, single-pass LDS-tile version: x is read from HBM exactly
// ONCE per element (old streaming prep read it twice: coalesced K-pass +
// semi-coalesced global V-gather). The 64x64 f32 tile lives in LDS; the K
// permuted read and the V transpose gather both hit LDS (transpose is
// conflict-free: 32 consecutive columns per half-wave). Output layouts are
// byte-identical to what gat_flash16 consumes.
__global__ __launch_bounds__(256) void prep_fused(
    const float* __restrict__ x, const int* __restrict__ adj,
    short* __restrict__ img, uint4v* __restrict__ mexp) {
  __shared__ float t[64 * 68];
  const int tid = threadIdx.x;
  const int c = blockIdx.x;   // 64-key window -> chunks 2c, 2c+1
  const int b = blockIdx.y;

  // load tile: row r, 16 floats at col cg*16 (4x float4, coalesced)
  {
    const int r = tid >> 2;
    const int cg = tid & 3;
    const float* src = x + ((size_t)(b * NN + c * 64 + r)) * DD + cg * 16;
#pragma unroll
    for (int hh = 0; hh < 4; ++hh)
      *(float4*)&t[r * 68 + cg * 16 + hh * 4] = ((const float4*)src)[hh];
  }
  __syncthreads();

  // K units (scaled by SQC, permuted rows): units 0..3 per chunk
#pragma unroll
  for (int i = 0; i < 2; ++i) {
    const int kc = tid + i * 256;
    const int u8 = kc >> 6, l = kc & 63;
    const int chl = u8 >> 2, dc = u8 & 3;
    const int m = l & 31, hA = l >> 5;
    const int lrow = chl * 32 + KEY_OF_ROW(m);
    const float* tr = &t[lrow * 68 + dc * 16 + 8 * hA];
    float4 f0 = ((const float4*)tr)[0];
    float4 f1 = ((const float4*)tr)[1];
    short8 v;
    v[0] = f2bf(f0.x * SQC); v[1] = f2bf(f0.y * SQC);
    v[2] = f2bf(f0.z * SQC); v[3] = f2bf(f0.w * SQC);
    v[4] = f2bf(f1.x * SQC); v[5] = f2bf(f1.y * SQC);
    v[6] = f2bf(f1.z * SQC); v[7] = f2bf(f1.w * SQC);
    *(short8*)&img[((size_t)(b * 64 + 2 * c + chl) * 8 + dc) * 512 + l * 8] = v;
  }
  // V units (transposed gather from LDS, natural key order): units 4..7
#pragma unroll
  for (int i = 0; i < 2; ++i) {
    const int vc = tid + i * 256;
    const int u8 = vc >> 6, l = vc & 63;
    const int chl = u8 >> 2, sub = u8 & 3;
    const int dh = sub >> 1, kh = sub & 1;
    const int d = dh * 32 + (l & 31);
    const int lk0 = chl * 32 + kh * 16 + 8 * (l >> 5);
    short8 o;
#pragma unroll
    for (int j = 0; j < 8; ++j) o[j] = f2bf(t[(lk0 + j) * 68 + d]);
    *(short8*)&img[((size_t)(b * 64 + 2 * c + chl) * 8 + 4 + sub) * 512 +
                   l * 8] = o;
  }

  // expanded masks (unchanged): block (c,b) -> tile (qg = b>>1, cm=2c+(b&1))
  if (tid < 128) {
    const int qg = b >> 1;
    const int cm = blockIdx.x * 2 + (b & 1);
    const int ql = tid;
    const int* ap = adj + (size_t)(qg * 128 + ql) * NN + cm * 32;
    int4v av[8];
#pragma unroll
    for (int j = 0; j < 8; ++j) av[j] = *(const int4v*)(ap + j * 4);
#pragma unroll
    for (int h = 0; h < 2; ++h) {
      uint4v mv;
#pragma unroll
      for (int wd = 0; wd < 4; ++wd) {
        unsigned word = 0;
#pragma unroll
        for (int tt = 0; tt < 4; ++tt) {
          const int K = 16 * (wd & 1) + 8 * h + 4 * (wd >> 1) + tt;
          word |= (av[K >> 2][K & 3] > 0 ? 0xFFu : 0u) << (8 * tt);
        }
        mv[wd] = word;
      }
      mexp[(((size_t)qg * 64 + (cm >> 1) * 2 + h) * 128 + ql) * 2 +
           (cm & 1)] = mv;
    }
  }
}

// masked bf16 pack of one chunk's 16 exp values -> pc0/pc1 B-frags
#define PACK_MASK(EV, MC, PC0, PC1)                                          \
  {                                                                          \
    short8 t0, t1;                                                           \
    t0[0] = f2bf(EV[0]);  t0[1] = f2bf(EV[1]);                               \
    t0[2] = f2bf(EV[2]);  t0[3] = f2bf(EV[3]);                               \
    t0[4] = f2bf(EV[8]);  t0[5] = f2bf(EV[9]);                               \
    t0[6] = f2bf(EV[10]); t0[7] = f2bf(EV[11]);                              \
    t1[0] = f2bf(EV[4]);  t1[1] = f2bf(EV[5]);                               \
    t1[2] = f2bf(EV[6]);  t1[3] = f2bf(EV[7]);                               \
    t1[4] = f2bf(EV[12]); t1[5] = f2bf(EV[13]);                              \
    t1[6] = f2bf(EV[14]); t1[7] = f2bf(EV[15]);                              \
    uint4v u0 = __builtin_bit_cast(uint4v, t0);                              \
    uint4v u1 = __builtin_bit_cast(uint4v, t1);                              \
    u0[0] &= __builtin_amdgcn_perm(0u, MC[0], 0x01010000u);                  \
    u0[1] &= __builtin_amdgcn_perm(0u, MC[0], 0x03030202u);                  \
    u0[2] &= __builtin_amdgcn_perm(0u, MC[2], 0x01010000u);                  \
    u0[3] &= __builtin_amdgcn_perm(0u, MC[2], 0x03030202u);                  \
    u1[0] &= __builtin_amdgcn_perm(0u, MC[1], 0x01010000u);                  \
    u1[1] &= __builtin_amdgcn_perm(0u, MC[1], 0x03030202u);                  \
    u1[2] &= __builtin_amdgcn_perm(0u, MC[3], 0x01010000u);                  \
    u1[3] &= __builtin_amdgcn_perm(0u, MC[3], 0x03030202u);                  \
    PC0 = __builtin_bit_cast(short8, u0);                                    \
    PC1 = __builtin_bit_cast(short8, u1);                                    \
  }

// One phase p (pair i = p): [vmcnt(VM)][barrier][load masks pair PAIRM]
// [stage KV pair PAIRS -> slot SLOTS][setprio(1) compute chunks 2i,2i+1 as
// two independent register streams][setprio(0)].  VMEM order per phase:
// 2 mask loads then 4 gload_lds, so vmcnt(4) at the next wait covers both
// this pair's KV (staged 2 phases ago) and its masks (loaded 1 phase ago).
#define PHASE_BODY(SLOT, MUE, MUO, MLE, MLO, VM, DO_MASK, PAIRM, DO_STAGE,   \
                   PAIRS, SLOTS)                                             \
  {                                                                          \
    asm volatile("s_waitcnt vmcnt(" VM ")" ::: "memory");                    \
    __builtin_amdgcn_s_barrier();                                            \
    const uint4v mE = MUE;                                                   \
    const uint4v mO = MUO;                                                   \
    if (DO_MASK) {                                                           \
      MLE = *(const uint4v*)(mpt + (size_t)(PAIRM) * 8192);                  \
      MLO = *(const uint4v*)(mpt + (size_t)(PAIRM) * 8192 + 16);             \
    }                                                                        \
    asm volatile("" ::: "memory");                                           \
    if (DO_STAGE) {                                                          \
      const short* gs_ = img_b + (size_t)(PAIRS) * 8192 + l * 8;             \
      short* ds_ = &sI[SLOTS][0];                                            \
      GLOAD_LDS16(gs_ + (w + 0) * 512, ds_ + (w + 0) * 512);                 \
      GLOAD_LDS16(gs_ + (w + 4) * 512, ds_ + (w + 4) * 512);                 \
      GLOAD_LDS16(gs_ + (w + 8) * 512, ds_ + (w + 8) * 512);                 \
      GLOAD_LDS16(gs_ + (w + 12) * 512, ds_ + (w + 12) * 512);               \
    }                                                                        \
    asm volatile("" ::: "memory");                                           \
    __builtin_amdgcn_s_setprio(1);                                           \
    const short* rE = &sI[SLOT][0];                                          \
    const short* rO = &sI[SLOT][4096];                                       \
    f32x16 sE = MFMA32B(*(const short8*)&rE[0 * 512 + l * 8], qf[0], fz);    \
    f32x16 sO = MFMA32B(*(const short8*)&rO[0 * 512 + l * 8], qf[0], fz);    \
    sE = MFMA32B(*(const short8*)&rE[1 * 512 + l * 8], qf[1], sE);           \
    sO = MFMA32B(*(const short8*)&rO[1 * 512 + l * 8], qf[1], sO);           \
    sE = MFMA32B(*(const short8*)&rE[2 * 512 + l * 8], qf[2], sE);           \
    sO = MFMA32B(*(const short8*)&rO[2 * 512 + l * 8], qf[2], sO);           \
    sE = MFMA32B(*(const short8*)&rE[3 * 512 + l * 8], qf[3], sE);           \
    sO = MFMA32B(*(const short8*)&rO[3 * 512 + l * 8], qf[3], sO);           \
    float eE[16], eO[16];                                                    \
    _Pragma("unroll") for (int r = 0; r < 16; ++r) {                         \
      eE[r] = fast_exp2(sE[r]);                                              \
      eO[r] = fast_exp2(sO[r]);                                              \
    }                                                                        \
    short8 pc0E, pc1E, pc0O, pc1O;                                           \
    PACK_MASK(eE, mE, pc0E, pc1E);                                           \
    PACK_MASK(eO, mO, pc0O, pc1O);                                           \
    acl = MFMA32B(ones8, pc0E, acl);                                         \
    acl = MFMA32B(ones8, pc1E, acl);                                         \
    acl = MFMA32B(ones8, pc0O, acl);                                         \
    acl = MFMA32B(ones8, pc1O, acl);                                         \
    accE[0] = MFMA32B(*(const short8*)&rE[4 * 512 + l * 8], pc0E, accE[0]);  \
    accO[0] = MFMA32B(*(const short8*)&rO[4 * 512 + l * 8], pc0O, accO[0]);  \
    accE[0] = MFMA32B(*(const short8*)&rE[5 * 512 + l * 8], pc1E, accE[0]);  \
    accO[0] = MFMA32B(*(const short8*)&rO[5 * 512 + l * 8], pc1O, accO[0]);  \
    accE[1] = MFMA32B(*(const short8*)&rE[6 * 512 + l * 8], pc0E, accE[1]);  \
    accO[1] = MFMA32B(*(const short8*)&rO[6 * 512 + l * 8], pc0O, accO[1]);  \
    accE[1] = MFMA32B(*(const short8*)&rE[7 * 512 + l * 8], pc1E, accE[1]);  \
    accO[1] = MFMA32B(*(const short8*)&rO[7 * 512 + l * 8], pc1O, accO[1]);  \
    __builtin_amdgcn_s_setprio(0);                                           \
  }

// ---------- main: gat_flash16 verbatim (measured best, 49.8 µs): 512
// blocks x 4 waves (2 blocks/CU), 2 independent chunk streams per phase,
// ring-3 of 16-KB pairs (48 KB LDS), counted vmcnt(4), E/O register-merged
// accumulators. beta&7 = XCD, 4 batches/XCD.
__global__ __launch_bounds__(256, 2) void gat_flash16(
    const float* __restrict__ x, const short* __restrict__ img,
    const char* __restrict__ mexp, float* __restrict__ out) {
  __shared__ short sI[3][8192];

  const int beta = blockIdx.x;
  const int xcd = beta & 7;
  const int idx = beta >> 3;       // 0..63
  const int qg = idx & 15;         // 128-row q-group
  const int b = xcd * 4 + (idx >> 4);

  const int tid = threadIdx.x;
  const int w = tid >> 6;
  const int l = tid & 63;
  const int h = l >> 5;
  const int ql = w * 32 + (l & 31);
  const int q = qg * 128 + ql;

  const short* img_b = img + (size_t)b * 64 * 8 * 512;
  const char* mpt =
      mexp + ((size_t)((qg * 64 + h) * 128) + ql) * 32;  // pair stride 8192 B

  // Q B-frags from x (scaled by SQC): qf[dc], elem j = Q[q, dc*16+8h+j]*SQC
  short8 qf[4];
  {
    const float* qs = x + ((size_t)(b * NN + q)) * DD + 8 * h;
#pragma unroll
    for (int dc = 0; dc < 4; ++dc) {
      float4 f0 = ((const float4*)(qs + dc * 16))[0];
      float4 f1 = ((const float4*)(qs + dc * 16))[1];
      short8 v;
      v[0] = f2bf(f0.x * SQC); v[1] = f2bf(f0.y * SQC);
      v[2] = f2bf(f0.z * SQC); v[3] = f2bf(f0.w * SQC);
      v[4] = f2bf(f1.x * SQC); v[5] = f2bf(f1.y * SQC);
      v[6] = f2bf(f1.z * SQC); v[7] = f2bf(f1.w * SQC);
      qf[dc] = v;
    }
  }

  f32x16 accE[2], accO[2], acl, fz;
#pragma unroll
  for (int z = 0; z < 16; ++z) {
    accE[0][z] = 0.f; accE[1][z] = 0.f;
    accO[0][z] = 0.f; accO[1][z] = 0.f;
    acl[z] = 0.f; fz[z] = 0.f;
  }

  short8 ones8;
#pragma unroll
  for (int j = 0; j < 8; ++j) ones8[j] = 0x3F80;

  uint4v mAE, mAO, mBE, mBO;

  // prologue: masks pair 0, then KV pairs 0,1 -> slots 0,1
  mAE = *(const uint4v*)(mpt);
  mAO = *(const uint4v*)(mpt + 16);
  asm volatile("" ::: "memory");
  {
    const short* gs_ = img_b + l * 8;
    GLOAD_LDS16(gs_ + (w + 0) * 512, &sI[0][(w + 0) * 512]);
    GLOAD_LDS16(gs_ + (w + 4) * 512, &sI[0][(w + 4) * 512]);
    GLOAD_LDS16(gs_ + (w + 8) * 512, &sI[0][(w + 8) * 512]);
    GLOAD_LDS16(gs_ + (w + 12) * 512, &sI[0][(w + 12) * 512]);
    const short* gs1_ = img_b + 8192 + l * 8;
    GLOAD_LDS16(gs1_ + (w + 0) * 512, &sI[1][(w + 0) * 512]);
    GLOAD_LDS16(gs1_ + (w + 4) * 512, &sI[1][(w + 4) * 512]);
    GLOAD_LDS16(gs1_ + (w + 8) * 512, &sI[1][(w + 8) * 512]);
    GLOAD_LDS16(gs1_ + (w + 12) * 512, &sI[1][(w + 12) * 512]);
  }
  asm volatile("" ::: "memory");

  // 32 phases; phase p computes pair p, loads masks p+1, stages KV p+2
  for (int M = 0; M < 5; ++M) {
    const int i0 = 6 * M;
    PHASE_BODY(0, mAE, mAO, mBE, mBO, "4", true, i0 + 1, true, i0 + 2, 2);
    PHASE_BODY(1, mBE, mBO, mAE, mAO, "4", true, i0 + 2, true, i0 + 3, 0);
    PHASE_BODY(2, mAE, mAO, mBE, mBO, "4", true, i0 + 3, true, i0 + 4, 1);
    PHASE_BODY(0, mBE, mBO, mAE, mAO, "4", true, i0 + 4, true, i0 + 5, 2);
    PHASE_BODY(1, mAE, mAO, mBE, mBO, "4", true, i0 + 5, true, i0 + 6, 0);
    PHASE_BODY(2, mBE, mBO, mAE, mAO, "4", true, i0 + 6, true, i0 + 7, 1);
  }
  PHASE_BODY(0, mAE, mAO, mBE, mBO, "4", true, 31, false, 0, 2);  // p=30
  PHASE_BODY(1, mBE, mBO, mAE, mAO, "0", false, 0, false, 0, 0);  // p=31

  // ---- epilogue: register merge of E/O partials, then write ----
  const float inv = 1.0f / acl[0];
  float* op = out + ((size_t)(b * NN + q)) * DD;
#pragma unroll
  for (int dh = 0; dh < 2; ++dh)
#pragma unroll
    for (int qd = 0; qd < 4; ++qd) {
      float4 o;
      o.x = (accE[dh][qd * 4 + 0] + accO[dh][qd * 4 + 0]) * inv;
      o.y = (accE[dh][qd * 4 + 1] + accO[dh][qd * 4 + 1]) * inv;
      o.z = (accE[dh][qd * 4 + 2] + accO[dh][qd * 4 + 2]) * inv;
      o.w = (accE[dh][qd * 4 + 3] + accO[dh][qd * 4 + 3]) * inv;
      *(float4*)(op + dh * 32 + 8 * qd + 4 * h) = o;
    }
}

extern "C" void kernel_launch(void* const* d_in, const int* in_sizes, int n_in,
                              void* d_out, int out_size, void* d_ws,
                              size_t ws_size, hipStream_t stream) {
  const float* x = (const float*)d_in[0];
  const int* adj = (const int*)d_in[1];
  float* out = (float*)d_out;

  short* img = (short*)d_ws;                                   // 16 MB
  uint4v* mexp = (uint4v*)(img + (size_t)NB * 64 * 8 * 512);   // 4 MB

  prep_fused<<<dim3(32, NB), 256, 0, stream>>>(x, adj, img, mexp);
  gat_flash16<<<512, 256, 0, stream>>>(x, img, (const char*)mexp, out);
}